// Round 11
// baseline (344.324 us; speedup 1.0000x reference)
//
#include <hip/hip_runtime.h>
#include <math.h>

#define NB 4
#define N 2000
#define DIN 128
#define DH 256
#define NROWS (NB*N)          // 8000
#define EPSF 1e-8f

typedef __attribute__((ext_vector_type(8))) short bf16x8;
typedef __attribute__((ext_vector_type(4))) float f32x4;

// ---------------- helpers ----------------

__device__ __forceinline__ float gelu_t(float x){
    // jax.nn.gelu approximate=True (tanh form)
    float z = 0.7978845608028654f * fmaf(0.044715f * x * x, x, x);
    z = fminf(fmaxf(z, -20.f), 20.f);
    float e = __expf(2.f * z);
    return 0.5f * x * (1.f + (e - 1.f) / (e + 1.f));
}

__device__ __forceinline__ unsigned short f2bf(float f){   // RNE f32->bf16 bits
    unsigned u = __float_as_uint(f);
    return (unsigned short)((u + 0x7FFFu + ((u >> 16) & 1u)) >> 16);
}

__device__ __forceinline__ unsigned f2mono(float f){
    unsigned b = __float_as_uint(f);
    return b ^ ((unsigned)(((int)b) >> 31) | 0x80000000u);
}
__device__ __forceinline__ float mono2f(unsigned u){
    unsigned b = (u & 0x80000000u) ? (u ^ 0x80000000u) : ~u;
    return __uint_as_float(b);
}

// full descending bitonic sort of 64 values across a wave (lane 0 = largest)
__device__ __forceinline__ float wave_sort64_desc(float v){
    const int lane = threadIdx.x & 63;
    #pragma unroll
    for (int k = 2; k <= 64; k <<= 1){
        #pragma unroll
        for (int j = k >> 1; j >= 1; j >>= 1){
            float o = __shfl_xor(v, j, 64);
            bool keepMax = ((lane & k) == 0) == ((lane & j) == 0);
            v = keepMax ? fmaxf(v, o) : fminf(v, o);
        }
    }
    return v;
}

// descending bitonic sort of 128 floats (2 regs/lane; element idx = 2*lane+r)
__device__ __forceinline__ void sort128_desc(float &v0, float &v1){
    const int lane = threadIdx.x & 63;
    #pragma unroll
    for (int k = 2; k <= 128; k <<= 1){
        #pragma unroll
        for (int j = k >> 1; j >= 2; j >>= 1){
            int lj = j >> 1;
            float o0 = __shfl_xor(v0, lj, 64);
            float o1 = __shfl_xor(v1, lj, 64);
            int idx0 = 2*lane, idx1 = 2*lane + 1;
            bool km0 = ((idx0 & k) == 0) == ((idx0 & j) == 0);
            bool km1 = ((idx1 & k) == 0) == ((idx1 & j) == 0);
            v0 = km0 ? fmaxf(v0, o0) : fminf(v0, o0);
            v1 = km1 ? fmaxf(v1, o1) : fminf(v1, o1);
        }
        {
            bool up = (((2*lane) & k) == 0);
            float a = fmaxf(v0, v1), b = fminf(v0, v1);
            v0 = up ? a : b;
            v1 = up ? b : a;
        }
    }
}

// descending bitonic sort of 128 u64 keys (2 regs/lane)
__device__ __forceinline__ void sort128_desc_u64(unsigned long long &v0, unsigned long long &v1){
    const int lane = threadIdx.x & 63;
    #pragma unroll
    for (int k = 2; k <= 128; k <<= 1){
        #pragma unroll
        for (int j = k >> 1; j >= 2; j >>= 1){
            int lj = j >> 1;
            unsigned long long o0 = __shfl_xor(v0, lj, 64);
            unsigned long long o1 = __shfl_xor(v1, lj, 64);
            int idx0 = 2*lane, idx1 = 2*lane + 1;
            bool km0 = ((idx0 & k) == 0) == ((idx0 & j) == 0);
            bool km1 = ((idx1 & k) == 0) == ((idx1 & j) == 0);
            unsigned long long a0 = (v0 > o0) ? v0 : o0, b0 = (v0 > o0) ? o0 : v0;
            unsigned long long a1 = (v1 > o1) ? v1 : o1, b1 = (v1 > o1) ? o1 : v1;
            v0 = km0 ? a0 : b0;
            v1 = km1 ? a1 : b1;
        }
        {
            bool up = (((2*lane) & k) == 0);
            unsigned long long a = (v0 > v1) ? v0 : v1, b = (v0 > v1) ? v1 : v0;
            v0 = up ? a : b;
            v1 = up ? b : a;
        }
    }
}

// Non-destructive wave-local exact 20th-largest fallback (register-only).
__device__ __forceinline__ float wave_topk20_slow32(const float (&v)[32]){
    float cur = 1e30f, kth = 0.f;
    int consumed = 0;
    for (int it = 0; it < 20; ++it){
        if (consumed >= 20) break;
        float bm = -3.f;
        #pragma unroll
        for (int i = 0; i < 32; ++i){ if (v[i] < cur) bm = fmaxf(bm, v[i]); }
        #pragma unroll
        for (int mm = 1; mm < 64; mm <<= 1) bm = fmaxf(bm, __shfl_xor(bm, mm, 64));
        int c = 0;
        #pragma unroll
        for (int i = 0; i < 32; ++i) c += (v[i] == bm) ? 1 : 0;
        #pragma unroll
        for (int mm = 1; mm < 64; mm <<= 1) c += __shfl_xor(c, mm, 64);
        consumed += c;
        kth = bm;
        cur = bm;
    }
    return kth;
}

// Exact wave-local 20th-largest (with multiplicity) of 64 lanes x 32 regs.
// Uniform barriers; MUST be called by ALL threads at the same program point.
__device__ __forceinline__ float wave_topk20_sync(const float (&v)[32], float* cl){
    const int lane = threadIdx.x & 63;
    float mx = v[0];
    #pragma unroll
    for (int i = 1; i < 32; ++i) mx = fmaxf(mx, v[i]);
    float sm = wave_sort64_desc(mx);
    float u = __shfl(sm, 19, 64);       // 20th-largest lane-max: u <= true kth
    int cnt = 0;
    #pragma unroll
    for (int i = 0; i < 32; ++i) cnt += (v[i] >= u) ? 1 : 0;
    int incl = cnt;
    #pragma unroll
    for (int s = 1; s < 64; s <<= 1){
        int o = __shfl_up(incl, s, 64);
        if (lane >= s) incl += o;
    }
    const int total = __shfl(incl, 63, 64);
    const bool fast = (total <= 128);   // wave-uniform
    if (fast){
        int offs = incl - cnt;
        #pragma unroll
        for (int i = 0; i < 32; ++i){
            if (v[i] >= u) cl[offs++] = v[i];
        }
    }
    __syncthreads();                    // uniform
    float kth;
    if (fast){
        float c0 = (2*lane     < total) ? cl[2*lane]     : -3.f;
        float c1 = (2*lane + 1 < total) ? cl[2*lane + 1] : -3.f;
        sort128_desc(c0, c1);
        kth = __shfl(c1, 9, 64);
    } else {
        kth = wave_topk20_slow32(v);
    }
    __syncthreads();                    // uniform
    return kth;
}

// Per-wave MFMA GEMM: out16x64 = A(16x256, bf16 LDS) @ Wt-slice.
__device__ __forceinline__ void mfma_gemm16(
    const unsigned short (*__restrict__ sA)[264], const unsigned short* __restrict__ Wt,
    int l15, int hi, int cbase, f32x4 acc[4])
{
    bf16x8 a[8];
    #pragma unroll
    for (int kb = 0; kb < 8; ++kb)
        a[kb] = *(const bf16x8*)&sA[l15][kb*32 + hi*8];
    __syncthreads();                     // all waves' A-frags in regs
    const unsigned short* wp0 = Wt + (size_t)(cbase      + l15)*256 + hi*8;
    const unsigned short* wp1 = Wt + (size_t)(cbase + 16 + l15)*256 + hi*8;
    const unsigned short* wp2 = Wt + (size_t)(cbase + 32 + l15)*256 + hi*8;
    const unsigned short* wp3 = Wt + (size_t)(cbase + 48 + l15)*256 + hi*8;
    #pragma unroll
    for (int kb = 0; kb < 8; ++kb){
        bf16x8 b0 = *(const bf16x8*)(wp0 + kb*32);
        bf16x8 b1 = *(const bf16x8*)(wp1 + kb*32);
        bf16x8 b2 = *(const bf16x8*)(wp2 + kb*32);
        bf16x8 b3 = *(const bf16x8*)(wp3 + kb*32);
        acc[0] = __builtin_amdgcn_mfma_f32_16x16x32_bf16(a[kb], b0, acc[0], 0, 0, 0);
        acc[1] = __builtin_amdgcn_mfma_f32_16x16x32_bf16(a[kb], b1, acc[1], 0, 0, 0);
        acc[2] = __builtin_amdgcn_mfma_f32_16x16x32_bf16(a[kb], b2, acc[2], 0, 0, 0);
        acc[3] = __builtin_amdgcn_mfma_f32_16x16x32_bf16(a[kb], b3, acc[3], 0, 0, 0);
    }
}

// ---------------- kernels ----------------

// Weight prep: Wt[m][c][k] = bf16(W[m][k][c]), 6 matrices 256x256. Grid (8,8,6).
__global__ __launch_bounds__(256) void k_wcvt(
    const float* __restrict__ w10, const float* __restrict__ w20,
    const float* __restrict__ w11, const float* __restrict__ w21,
    const float* __restrict__ gw1, const float* __restrict__ gw2,
    unsigned short* __restrict__ Wt)
{
    __shared__ float t[32][33];
    const int m = blockIdx.z;
    const float* W = (m==0)?w10:(m==1)?w20:(m==2)?w11:(m==3)?w21:(m==4)?gw1:gw2;
    unsigned short* out = Wt + (size_t)m*65536;
    const int k0 = blockIdx.y*32, c0 = blockIdx.x*32;
    const int tx = threadIdx.x & 31, ty = threadIdx.x >> 5;
    #pragma unroll
    for (int j = 0; j < 4; ++j){
        int k = ty*4 + j;
        t[k][tx] = W[(size_t)(k0+k)*256 + c0+tx];
    }
    __syncthreads();
    #pragma unroll
    for (int j = 0; j < 4; ++j){
        int c = ty*4 + j;
        out[(size_t)(c0+c)*256 + k0+tx] = f2bf(t[tx][c]);
    }
}

// Encoder bottleneck + projection + FDG embedding. 8 rows/block, 1000 blocks.
__global__ __launch_bounds__(256) void k_enc(
    const float* __restrict__ X,
    const float* __restrict__ lg, const float* __restrict__ lb,
    const float* __restrict__ w1, const float* __restrict__ b1,
    const float* __restrict__ w2, const float* __restrict__ b2,
    const float* __restrict__ pw, const float* __restrict__ pb,
    const float* __restrict__ fB,
    float* __restrict__ hid, float* __restrict__ Zn)
{
    __shared__ float sH[8][132];
    __shared__ float sT[8][68];
    __shared__ float sXm[8][132];
    const int tid = threadIdx.x;
    const int lane = tid & 63;
    const int wave = tid >> 6;
    const int rg = wave * 2;
    const int row0 = blockIdx.x * 8;
    const int cx = lane * 2;
    float2 x0 = *(const float2*)(X + (size_t)(row0+rg  )*128 + cx);
    float2 x1 = *(const float2*)(X + (size_t)(row0+rg+1)*128 + cx);
    {
        float sa = x0.x + x0.y, sb = x1.x + x1.y;
        float qa = x0.x*x0.x + x0.y*x0.y, qb = x1.x*x1.x + x1.y*x1.y;
        #pragma unroll
        for (int m = 1; m < 64; m <<= 1){
            sa += __shfl_xor(sa, m, 64); sb += __shfl_xor(sb, m, 64);
            qa += __shfl_xor(qa, m, 64); qb += __shfl_xor(qb, m, 64);
        }
        float mua = sa*(1.f/128.f), mub = sb*(1.f/128.f);
        float rsa = rsqrtf(qa*(1.f/128.f) - mua*mua + 1e-5f);
        float rsb = rsqrtf(qb*(1.f/128.f) - mub*mub + 1e-5f);
        float2 gg = *(const float2*)(lg + cx);
        float2 bb = *(const float2*)(lb + cx);
        sH[rg  ][cx] = (x0.x - mua)*rsa*gg.x + bb.x;
        sH[rg  ][cx+1] = (x0.y - mua)*rsa*gg.y + bb.y;
        sH[rg+1][cx] = (x1.x - mub)*rsb*gg.x + bb.x;
        sH[rg+1][cx+1] = (x1.y - mub)*rsb*gg.y + bb.y;
    }
    __syncthreads();
    {
        float a0 = 0.f, a1 = 0.f;
        #pragma unroll 4
        for (int k = 0; k < 128; ++k){
            float h0 = sH[rg][k], h1 = sH[rg+1][k];
            float wk = w1[k*64 + lane];
            a0 = fmaf(h0, wk, a0);
            a1 = fmaf(h1, wk, a1);
        }
        float bb = b1[lane];
        sT[rg  ][lane] = gelu_t(a0 + bb);
        sT[rg+1][lane] = gelu_t(a1 + bb);
    }
    __syncthreads();
    {
        float p0x=0.f,p0y=0.f,p1x=0.f,p1y=0.f;
        #pragma unroll 4
        for (int k = 0; k < 64; ++k){
            float t0 = sT[rg][k], t1 = sT[rg+1][k];
            float2 w = *(const float2*)(w2 + k*128 + cx);
            p0x = fmaf(t0, w.x, p0x); p0y = fmaf(t0, w.y, p0y);
            p1x = fmaf(t1, w.x, p1x); p1y = fmaf(t1, w.y, p1y);
        }
        float2 bb = *(const float2*)(b2 + cx);
        sXm[rg  ][cx]   = x0.x + p0x + bb.x;
        sXm[rg  ][cx+1] = x0.y + p0y + bb.y;
        sXm[rg+1][cx]   = x1.x + p1x + bb.x;
        sXm[rg+1][cx+1] = x1.y + p1y + bb.y;
    }
    __syncthreads();
    {
        const int ri = lane >> 4;
        const int wc = wave*64 + (lane & 15)*4;
        float a0[4] = {0,0,0,0}, a1[4] = {0,0,0,0};
        #pragma unroll 4
        for (int k = 0; k < 128; ++k){
            float h0 = sXm[ri*2][k], h1 = sXm[ri*2+1][k];
            float4 w = *(const float4*)(pw + k*256 + wc);
            a0[0]=fmaf(h0,w.x,a0[0]); a0[1]=fmaf(h0,w.y,a0[1]); a0[2]=fmaf(h0,w.z,a0[2]); a0[3]=fmaf(h0,w.w,a0[3]);
            a1[0]=fmaf(h1,w.x,a1[0]); a1[1]=fmaf(h1,w.y,a1[1]); a1[2]=fmaf(h1,w.z,a1[2]); a1[3]=fmaf(h1,w.w,a1[3]);
        }
        float4 bb = *(const float4*)(pb + wc);
        float4 o0 = make_float4(a0[0]+bb.x, a0[1]+bb.y, a0[2]+bb.z, a0[3]+bb.w);
        float4 o1 = make_float4(a1[0]+bb.x, a1[1]+bb.y, a1[2]+bb.z, a1[3]+bb.w);
        *(float4*)(hid + (size_t)(row0+ri*2  )*256 + wc) = o0;
        *(float4*)(hid + (size_t)(row0+ri*2+1)*256 + wc) = o1;
    }
    if (tid < 128){
        const int r = tid >> 4, q = tid & 15;
        float z = 0.f;
        #pragma unroll 4
        for (int k = 0; k < 128; ++k) z = fmaf(sXm[r][k], fB[q*128 + k], z);
        float s2 = z*z;
        #pragma unroll
        for (int m = 1; m < 16; m <<= 1) s2 += __shfl_xor(s2, m, 64);
        Zn[(size_t)(row0 + r)*16 + q] = z / (sqrtf(s2) + EPSF);
    }
}

// history -> normalized (pre-scaled by 1/8), stored TRANSPOSED: HnT[b][t][n]
__global__ __launch_bounds__(256) void k_hist(const float* __restrict__ H, float* __restrict__ HnT)
{
    const int row  = blockIdx.x * 4 + (threadIdx.x >> 6);
    const int lane = threadIdx.x & 63;
    float v = H[(size_t)row*64 + lane];
    float s = v;
    #pragma unroll
    for (int mm = 1; mm < 64; mm <<= 1) s += __shfl_xor(s, mm, 64);
    float mu = s * (1.f/64.f);
    float d = v - mu;
    float s2 = d*d;
    #pragma unroll
    for (int mm = 1; mm < 64; mm <<= 1) s2 += __shfl_xor(s2, mm, 64);
    float sd = sqrtf(s2 * (1.f/64.f));
    const int b = row / N, nloc = row % N;
    HnT[(size_t)b*64*N + (size_t)lane*N + nloc] = d / ((sd + EPSF) * 8.f);
}

// Fused residual MLP blocks 0+1 + gblk-LN (hh). MFMA bf16. 16 rows/block.
__global__ __launch_bounds__(256) void k_mlp2(
    float* __restrict__ hid, const unsigned short* __restrict__ Wtb,
    const float* __restrict__ g0, const float* __restrict__ be0,
    const float* __restrict__ b10, const float* __restrict__ b20,
    const float* __restrict__ g1, const float* __restrict__ be1,
    const float* __restrict__ b11, const float* __restrict__ b21,
    const float* __restrict__ hg, const float* __restrict__ hb,
    float* __restrict__ hh_out)
{
    __shared__ float sR[16][264];
    __shared__ unsigned short sA[16][264];
    const int tid = threadIdx.x;
    const int lane = tid & 63, wave = tid >> 6;
    const int l15 = lane & 15, hi = lane >> 4;
    const int cbase = wave * 64;
    const int row0 = blockIdx.x * 16;
    {
        const int r = tid >> 4, cb = (tid & 15) * 4;
        #pragma unroll
        for (int q = 0; q < 4; ++q)
            *(float4*)&sR[r][cb + q*64] =
                *(const float4*)(hid + (size_t)(row0+r)*256 + cb + q*64);
    }
    __syncthreads();
    #pragma unroll
    for (int it = 0; it < 2; ++it){
        const float* g  = it ? g1  : g0;
        const float* be = it ? be1 : be0;
        const float* B1 = it ? b11 : b10;
        const float* B2 = it ? b21 : b20;
        const unsigned short* W1 = Wtb + (size_t)(it ? 2 : 0)*65536;
        const unsigned short* W2 = Wtb + (size_t)(it ? 3 : 1)*65536;
        {
            float4 gg = *(const float4*)(g + lane*4);
            float4 bb = *(const float4*)(be + lane*4);
            #pragma unroll
            for (int j = 0; j < 4; ++j){
                const int r = wave*4 + j;
                float4 v = *(const float4*)&sR[r][lane*4];
                float s = v.x+v.y+v.z+v.w;
                float q = v.x*v.x+v.y*v.y+v.z*v.z+v.w*v.w;
                #pragma unroll
                for (int m = 1; m < 64; m <<= 1){
                    s += __shfl_xor(s, m, 64); q += __shfl_xor(q, m, 64);
                }
                float mu = s*(1.f/256.f);
                float rs = rsqrtf(q*(1.f/256.f) - mu*mu + 1e-5f);
                ushort4 o;
                o.x = f2bf((v.x-mu)*rs*gg.x+bb.x);
                o.y = f2bf((v.y-mu)*rs*gg.y+bb.y);
                o.z = f2bf((v.z-mu)*rs*gg.z+bb.z);
                o.w = f2bf((v.w-mu)*rs*gg.w+bb.w);
                *(ushort4*)&sA[r][lane*4] = o;
            }
        }
        __syncthreads();
        {
            f32x4 acc[4];
            #pragma unroll
            for (int t = 0; t < 4; ++t){ acc[t][0]=0.f; acc[t][1]=0.f; acc[t][2]=0.f; acc[t][3]=0.f; }
            mfma_gemm16(sA, W1, l15, hi, cbase, acc);
            #pragma unroll
            for (int t = 0; t < 4; ++t){
                int ct = cbase + t*16 + l15;
                float bbx = B1[ct];
                #pragma unroll
                for (int j = 0; j < 4; ++j)
                    sA[hi*4 + j][ct] = f2bf(gelu_t(acc[t][j] + bbx));
            }
        }
        __syncthreads();
        {
            f32x4 acc[4];
            #pragma unroll
            for (int t = 0; t < 4; ++t){ acc[t][0]=0.f; acc[t][1]=0.f; acc[t][2]=0.f; acc[t][3]=0.f; }
            mfma_gemm16(sA, W2, l15, hi, cbase, acc);
            #pragma unroll
            for (int t = 0; t < 4; ++t){
                int ct = cbase + t*16 + l15;
                float bbx = B2[ct];
                #pragma unroll
                for (int j = 0; j < 4; ++j)
                    sR[hi*4 + j][ct] += acc[t][j] + bbx;
            }
        }
        __syncthreads();
    }
    {
        const int r = tid >> 4, cb = (tid & 15) * 4;
        #pragma unroll
        for (int q = 0; q < 4; ++q)
            *(float4*)(hid + (size_t)(row0+r)*256 + cb + q*64) =
                *(const float4*)&sR[r][cb + q*64];
    }
    {
        float4 gg = *(const float4*)(hg + lane*4);
        float4 bb = *(const float4*)(hb + lane*4);
        #pragma unroll
        for (int j = 0; j < 4; ++j){
            const int r = wave*4 + j;
            float4 v = *(const float4*)&sR[r][lane*4];
            float s = v.x+v.y+v.z+v.w;
            float q = v.x*v.x+v.y*v.y+v.z*v.z+v.w*v.w;
            #pragma unroll
            for (int m = 1; m < 64; m <<= 1){
                s += __shfl_xor(s, m, 64); q += __shfl_xor(q, m, 64);
            }
            float mu = s*(1.f/256.f);
            float rs = rsqrtf(q*(1.f/256.f) - mu*mu + 1e-5f);
            float4 o = make_float4((v.x-mu)*rs*gg.x+bb.x, (v.y-mu)*rs*gg.y+bb.y,
                                   (v.z-mu)*rs*gg.z+bb.z, (v.w-mu)*rs*gg.w+bb.w);
            *(float4*)(hh_out + (size_t)(row0+r)*256 + lane*4) = o;
        }
    }
}

// Fused corr GEMM + exact per-row top-20 of rc (no rc materialization).
// Grid (125, NB); 16 rows/block; wave owns 4 rows. Two GEMM passes over m:
// pass 1 tracks per-lane row max/sum (u = 20th of 64 lane-maxes => exact
// lower bound with count>=20); pass 2 recomputes identical values and
// compacts candidates >= u into LDS; epilogue sorts and emits boost lists.
// Rows whose candidate count exceeds 128 are flagged for k_fix.
__global__ __launch_bounds__(256) void k_corrtop(
    const float* __restrict__ HnTb, const float* __restrict__ mixlog,
    int* __restrict__ bidxA, float* __restrict__ boostA,
    int* __restrict__ cntA, int* __restrict__ flagA)
{
    __shared__ float sA[64][16];
    __shared__ float sB[64][128];
    __shared__ float cval[16][128];
    __shared__ int   cidxs[16][128];
    const int tid = threadIdx.x;
    const int lane = tid & 63, wv = tid >> 6;
    const int bz = blockIdx.y;
    const int n0 = blockIdx.x * 16;
    const float* H = HnTb + (size_t)bz * 64 * N;
    const unsigned long long lt = (1ull << lane) - 1ull;
    #pragma unroll
    for (int j = 0; j < 4; ++j){
        int idx = tid + 256*j;
        int k = idx >> 4, r = idx & 15;
        sA[k][r] = H[(size_t)k*N + n0 + r];
    }
    float mxr[4] = {0.f,0.f,0.f,0.f}, smr[4] = {0.f,0.f,0.f,0.f};
    // ---- pass 1: GEMM + max/sum ----
    for (int mc = 0; mc < N; mc += 128){
        __syncthreads();
        #pragma unroll
        for (int q = 0; q < 8; ++q){
            int f = tid + 256*q;
            int k = f >> 5, c4 = (f & 31) * 4;
            int m = mc + c4;
            float4 v = (m + 3 < N) ? *(const float4*)(H + (size_t)k*N + m)
                                   : make_float4(0.f,0.f,0.f,0.f);
            *(float4*)&sB[k][c4] = v;
        }
        __syncthreads();
        float acc[4][2] = {{0.f,0.f},{0.f,0.f},{0.f,0.f},{0.f,0.f}};
        #pragma unroll 4
        for (int k = 0; k < 64; ++k){
            float2 b2v = *(const float2*)&sB[k][lane*2];
            #pragma unroll
            for (int r = 0; r < 4; ++r){
                float a = sA[k][wv*4 + r];
                acc[r][0] = fmaf(a, b2v.x, acc[r][0]);
                acc[r][1] = fmaf(a, b2v.y, acc[r][1]);
            }
        }
        #pragma unroll
        for (int r = 0; r < 4; ++r){
            float v0 = fmaxf(acc[r][0], 0.f), v1 = fmaxf(acc[r][1], 0.f);
            smr[r] += v0 + v1;
            mxr[r] = fmaxf(mxr[r], fmaxf(v0, v1));
        }
    }
    float u[4], sumC[4];
    #pragma unroll
    for (int r = 0; r < 4; ++r){
        float sm = wave_sort64_desc(mxr[r]);
        u[r] = __shfl(sm, 19, 64);
        float s = smr[r];
        #pragma unroll
        for (int mm = 1; mm < 64; mm <<= 1) s += __shfl_xor(s, mm, 64);
        sumC[r] = s;
    }
    int cnt[4] = {0,0,0,0};
    // ---- pass 2: identical GEMM + candidate compaction ----
    for (int mc = 0; mc < N; mc += 128){
        __syncthreads();
        #pragma unroll
        for (int q = 0; q < 8; ++q){
            int f = tid + 256*q;
            int k = f >> 5, c4 = (f & 31) * 4;
            int m = mc + c4;
            float4 v = (m + 3 < N) ? *(const float4*)(H + (size_t)k*N + m)
                                   : make_float4(0.f,0.f,0.f,0.f);
            *(float4*)&sB[k][c4] = v;
        }
        __syncthreads();
        float acc[4][2] = {{0.f,0.f},{0.f,0.f},{0.f,0.f},{0.f,0.f}};
        #pragma unroll 4
        for (int k = 0; k < 64; ++k){
            float2 b2v = *(const float2*)&sB[k][lane*2];
            #pragma unroll
            for (int r = 0; r < 4; ++r){
                float a = sA[k][wv*4 + r];
                acc[r][0] = fmaf(a, b2v.x, acc[r][0]);
                acc[r][1] = fmaf(a, b2v.y, acc[r][1]);
            }
        }
        #pragma unroll
        for (int r = 0; r < 4; ++r){
            const int row = wv*4 + r;
            float v0 = fmaxf(acc[r][0], 0.f), v1 = fmaxf(acc[r][1], 0.f);
            bool c0 = (v0 >= u[r]);
            unsigned long long mk = __ballot(c0);
            int off = cnt[r] + (int)__popcll(mk & lt);
            if (c0 && off < 128){ cval[row][off] = v0; cidxs[row][off] = mc + lane*2; }
            cnt[r] += (int)__popcll(mk);
            bool c1 = (v1 >= u[r]);
            mk = __ballot(c1);
            off = cnt[r] + (int)__popcll(mk & lt);
            if (c1 && off < 128){ cval[row][off] = v1; cidxs[row][off] = mc + lane*2 + 1; }
            cnt[r] += (int)__popcll(mk);
        }
    }
    __syncthreads();                    // fences candidate writes (uniform)
    const float mixw = 1.f / (1.f + __expf(-mixlog[0]));
    const float onemix = 1.f - mixw;
    #pragma unroll
    for (int r = 0; r < 4; ++r){
        const int row = wv*4 + r;
        const int ck = (cnt[r] < 128) ? cnt[r] : 128;
        const int p0 = 2*lane, p1 = 2*lane + 1;
        unsigned long long k0 = (p0 < ck)
            ? ((((unsigned long long)f2mono(cval[row][p0])) << 32) | (unsigned)cidxs[row][p0]) : 0ull;
        unsigned long long k1 = (p1 < ck)
            ? ((((unsigned long long)f2mono(cval[row][p1])) << 32) | (unsigned)cidxs[row][p1]) : 0ull;
        sort128_desc_u64(k0, k1);
        unsigned long long kk = __shfl(k1, 9, 64);       // rank 19
        float ckth = mono2f((unsigned)(kk >> 32));
        float a0 = mono2f((unsigned)(k0 >> 32));
        float a1 = mono2f((unsigned)(k1 >> 32));
        // NaN (sentinel decode) compares false everywhere
        float sklL = ((a0 >= ckth) ? a0 : 0.f) + ((a1 >= ckth) ? a1 : 0.f);
        #pragma unroll
        for (int mm = 1; mm < 64; mm <<= 1) sklL += __shfl_xor(sklL, mm, 64);
        bool q0 = (a0 >= ckth) && (a0 > 0.f);
        bool q1 = (a1 >= ckth) && (a1 > 0.f);
        int KL = (q0 ? 1 : 0) + (q1 ? 1 : 0);
        #pragma unroll
        for (int mm = 1; mm < 64; mm <<= 1) KL += __shfl_xor(KL, mm, 64);
        float r1v = 1.f / (sumC[r] + EPSF);
        float rollsc = r1v * (1.f / (sklL * r1v + EPSF));
        const int n = bz*N + n0 + row;
        if (q0 && p0 < 24){ bidxA[n*24 + p0] = (int)(k0 & 0xffffffffu); boostA[n*24 + p0] = onemix * a0 * rollsc; }
        if (q1 && p1 < 24){ bidxA[n*24 + p1] = (int)(k1 & 0xffffffffu); boostA[n*24 + p1] = onemix * a1 * rollsc; }
        if (lane == 0){
            cntA[n] = (KL < 24) ? KL : 24;
            flagA[n] = (cnt[r] > 128) ? 1 : 0;
        }
    }
}

// Exact fixup for (rare) overflow-flagged rows: recompute the full rc row
// and redo the top-20/boost emission. One wave per row; early-exit if clean.
__global__ __launch_bounds__(64) void k_fix(
    const float* __restrict__ HnTb, const float* __restrict__ mixlog,
    int* __restrict__ bidxA, float* __restrict__ boostA,
    int* __restrict__ cntA, const int* __restrict__ flagA)
{
    const int n = blockIdx.x;
    if (flagA[n] == 0) return;
    const int lane = threadIdx.x & 63;
    const int b = n / N, nloc = n % N;
    const float* H = HnTb + (size_t)b * 64 * N;
    float acc[32];
    #pragma unroll
    for (int i = 0; i < 32; ++i) acc[i] = 0.f;
    for (int t = 0; t < 64; ++t){
        float ht = H[(size_t)t*N + nloc];
        const float* Hr = H + (size_t)t*N;
        #pragma unroll
        for (int i = 0; i < 32; ++i){
            int m = lane + 64*i;
            if (m < N) acc[i] = fmaf(ht, Hr[m], acc[i]);
        }
    }
    float rcv[32], v[32];
    float sumC = 0.f;
    #pragma unroll
    for (int i = 0; i < 32; ++i){
        int m = lane + 64*i;
        float x = (m < N) ? fmaxf(acc[i], 0.f) : -1.f;
        rcv[i] = x; v[i] = x;
        if (x >= 0.f) sumC += x;
    }
    #pragma unroll
    for (int mm = 1; mm < 64; mm <<= 1) sumC += __shfl_xor(sumC, mm, 64);
    unsigned long long wins[20];
    for (int it = 0; it < 20; ++it){
        float bm = v[0]; int bi = 0;
        #pragma unroll
        for (int i = 1; i < 32; ++i){ if (v[i] > bm){ bm = v[i]; bi = i; } }
        unsigned long long mykey =
            (((unsigned long long)f2mono(bm)) << 32) | (unsigned)(lane + 64*bi);
        unsigned long long win = mykey;
        #pragma unroll
        for (int mm = 1; mm < 64; mm <<= 1){
            unsigned long long o = __shfl_xor(win, mm, 64);
            win = (o > win) ? o : win;
        }
        bool me = (win == mykey);
        #pragma unroll
        for (int i = 0; i < 32; ++i){ if (me && (i == bi)) v[i] = -2.f; }
        wins[it] = win;
    }
    float ckth = mono2f((unsigned)(wins[19] >> 32));
    float skl = 0.f;
    #pragma unroll
    for (int i = 0; i < 32; ++i){ if (rcv[i] >= ckth && rcv[i] >= 0.f) skl += rcv[i]; }
    #pragma unroll
    for (int mm = 1; mm < 64; mm <<= 1) skl += __shfl_xor(skl, mm, 64);
    const float mixw = 1.f / (1.f + __expf(-mixlog[0]));
    const float onemix = 1.f - mixw;
    float r1v = 1.f / (sumC + EPSF);
    float rollsc = r1v * (1.f / (skl * r1v + EPSF));
    if (lane == 0){
        int K = 0;
        #pragma unroll
        for (int it = 0; it < 20; ++it){
            float va = mono2f((unsigned)(wins[it] >> 32));
            int mi = (int)(wins[it] & 0xffffffffu);
            if (va > 0.f && K < 24){
                bidxA[n*24 + K] = mi;
                boostA[n*24 + K] = onemix * va * rollsc;
                ++K;
            }
        }
        cntA[n] = K;
    }
}

// Selection without rc: per row, softmax dots + ONE exact top-20 (on e) +
// 40-candidate exact merge with the precomputed boost list + gather.
// One row per wave, 4 rows/block. Uniform barriers only.
__global__ __launch_bounds__(256) void k_sel2(
    const float* __restrict__ Zn, const float* __restrict__ hh,
    const float* __restrict__ mixlog,
    const int* __restrict__ bidxA, const float* __restrict__ boostA,
    const int* __restrict__ cntA,
    float* __restrict__ msg)
{
    __shared__ float cl[4][128];
    __shared__ float camv[4][128];
    __shared__ int   cidx[4][128];
    __shared__ int   bli[4][24];
    __shared__ float blb[4][24];
    __shared__ int   lmb[4][32];
    __shared__ float lvb[4][32];
    const int tid = threadIdx.x;
    const int lane = tid & 63, wv = tid >> 6;
    const int n = blockIdx.x * 4 + wv;
    const int base = (n / N) * N;
    const unsigned long long lt = (1ull << lane) - 1ull;
    float zr[16];
    {
        const float* zp = Zn + (size_t)n * 16;
        #pragma unroll
        for (int q = 0; q < 16; ++q) zr[q] = zp[q];
    }
    float e_[32];
    float sumE = 0.f;
    #pragma unroll
    for (int i = 0; i < 32; ++i){
        const int m = lane + 64*i;
        float e = 0.f;
        if (m < N){
            const float4* zp = (const float4*)(Zn + (size_t)(base + m) * 16);
            float4 za = zp[0], zb = zp[1], zc = zp[2], zd = zp[3];
            float s = za.x * zr[0];
            s = fmaf(za.y, zr[1], s);  s = fmaf(za.z, zr[2], s);  s = fmaf(za.w, zr[3], s);
            s = fmaf(zb.x, zr[4], s);  s = fmaf(zb.y, zr[5], s);  s = fmaf(zb.z, zr[6], s);
            s = fmaf(zb.w, zr[7], s);  s = fmaf(zc.x, zr[8], s);  s = fmaf(zc.y, zr[9], s);
            s = fmaf(zc.z, zr[10], s); s = fmaf(zc.w, zr[11], s); s = fmaf(zd.x, zr[12], s);
            s = fmaf(zd.y, zr[13], s); s = fmaf(zd.z, zr[14], s); s = fmaf(zd.w, zr[15], s);
            e = __expf(s);             // |s| <= 1
            sumE += e;
        }
        e_[i] = e;
    }
    #pragma unroll
    for (int mm = 1; mm < 64; mm <<= 1) sumE += __shfl_xor(sumE, mm, 64);
    float ekth = wave_topk20_sync(e_, cl[wv]);   // barriers 1,2 (uniform)
    const int cntB = cntA[n];
    if (lane < cntB && lane < 24){
        bli[wv][lane] = bidxA[(size_t)n*24 + lane];
        blb[wv][lane] = boostA[(size_t)n*24 + lane];
    }
    const float mixw = 1.f / (1.f + __expf(-mixlog[0]));
    const float invSumE = 1.f / sumE;
    // dense candidates: e >= ekth
    int cnt = 0;
    #pragma unroll
    for (int i = 0; i < 32; ++i) cnt += (e_[i] >= ekth) ? 1 : 0;
    int incl = cnt;
    #pragma unroll
    for (int s = 1; s < 64; s <<= 1){
        int o = __shfl_up(incl, s, 64);
        if (lane >= s) incl += o;
    }
    int dtotal = __shfl(incl, 63, 64);
    if (dtotal > 104) dtotal = 104;
    int offs = incl - cnt;
    #pragma unroll
    for (int i = 0; i < 32; ++i){
        if (e_[i] >= ekth){
            if (offs < 104){
                camv[wv][offs] = mixw * e_[i] * invSumE;
                cidx[wv][offs] = lane + 64*i;
            }
            offs++;
        }
    }
    __syncthreads();                    // barrier 3 (uniform)
    // merge boosts
    bool nf = false; int m_b = 0; float amNew = 0.f;
    if (lane < cntB && lane < 24){
        m_b = bli[wv][lane];
        float bo = blb[wv][lane];
        int found = -1;
        for (int s = 0; s < dtotal; ++s){
            if (cidx[wv][s] == m_b){ found = s; break; }
        }
        if (found >= 0){
            camv[wv][found] += bo;
        } else {
            const float4* zp = (const float4*)(Zn + (size_t)(base + m_b) * 16);
            float4 za = zp[0], zb = zp[1], zc = zp[2], zd = zp[3];
            float s = za.x * zr[0];
            s = fmaf(za.y, zr[1], s);  s = fmaf(za.z, zr[2], s);  s = fmaf(za.w, zr[3], s);
            s = fmaf(zb.x, zr[4], s);  s = fmaf(zb.y, zr[5], s);  s = fmaf(zb.z, zr[6], s);
            s = fmaf(zb.w, zr[7], s);  s = fmaf(zc.x, zr[8], s);  s = fmaf(zc.y, zr[9], s);
            s = fmaf(zc.z, zr[10], s); s = fmaf(zc.w, zr[11], s); s = fmaf(zd.x, zr[12], s);
            s = fmaf(zd.y, zr[13], s); s = fmaf(zd.z, zr[14], s); s = fmaf(zd.w, zr[15], s);
            float e2 = __expf(s);
            amNew = mixw * e2 * invSumE + bo;
            nf = true;
        }
    }
    unsigned long long mk = __ballot(nf);
    if (nf){
        int off2 = dtotal + (int)__popcll(mk & lt);
        if (off2 < 128){ camv[wv][off2] = amNew; cidx[wv][off2] = m_b; }
    }
    int atotal = dtotal + (int)__popcll(mk);
    if (atotal > 128) atotal = 128;
    float SB = (lane < cntB && lane < 24) ? blb[wv][lane] : 0.f;
    #pragma unroll
    for (int mm = 1; mm < 64; mm <<= 1) SB += __shfl_xor(SB, mm, 64);
    __syncthreads();                    // barrier 4 (uniform)
    const int p0 = 2*lane, p1 = 2*lane + 1;
    unsigned long long k0 = (p0 < atotal)
        ? ((((unsigned long long)f2mono(camv[wv][p0])) << 32) | (unsigned)cidx[wv][p0]) : 0ull;
    unsigned long long k1 = (p1 < atotal)
        ? ((((unsigned long long)f2mono(camv[wv][p1])) << 32) | (unsigned)cidx[wv][p1]) : 0ull;
    sort128_desc_u64(k0, k1);
    unsigned long long kk = __shfl(k1, 9, 64);   // rank 19
    float am_kth = mono2f((unsigned)(kk >> 32));
    float a0 = mono2f((unsigned)(k0 >> 32));
    float a1 = mono2f((unsigned)(k1 >> 32));
    bool va0 = (p0 < atotal) && (a0 >= am_kth);  // NaN sentinel -> false
    bool va1 = (p1 < atotal) && (a1 >= am_kth);
    float sk2 = (va0 ? a0 : 0.f) + (va1 ? a1 : 0.f);
    #pragma unroll
    for (int mm = 1; mm < 64; mm <<= 1) sk2 += __shfl_xor(sk2, mm, 64);
    int K = (va0 ? 1 : 0) + (va1 ? 1 : 0);
    #pragma unroll
    for (int mm = 1; mm < 64; mm <<= 1) K += __shfl_xor(K, mm, 64);
    if (K > 32) K = 32;
    const float sumAm = mixw + SB;      // closed-form row sum of mixed weights
    const float ra = 1.f / (sumAm + EPSF);
    const float fsc = ra * (1.f / (sk2 * ra + EPSF));
    if (va0 && p0 < 32){ lmb[wv][p0] = (int)(k0 & 0xffffffffu); lvb[wv][p0] = a0 * fsc; }
    if (va1 && p1 < 32){ lmb[wv][p1] = (int)(k1 & 0xffffffffu); lvb[wv][p1] = a1 * fsc; }
    __syncthreads();                    // barrier 5 (uniform)
    float g0 = 0.f, g1 = 0.f, g2 = 0.f, g3 = 0.f;
    for (int k = 0; k < K; ++k){
        float w = lvb[wv][k];
        const float4 hv = *(const float4*)(hh + ((size_t)(base + lmb[wv][k]))*256 + lane*4);
        g0 = fmaf(w, hv.x, g0); g1 = fmaf(w, hv.y, g1);
        g2 = fmaf(w, hv.z, g2); g3 = fmaf(w, hv.w, g3);
    }
    *(float4*)(msg + (size_t)n*256 + lane*4) = make_float4(g0, g1, g2, g3);
}

// Graph-residual MLP + head. MFMA bf16. 16 rows/block, 500 blocks.
__global__ __launch_bounds__(256) void k_gblk(
    const float* __restrict__ hid, const float* __restrict__ msgb,
    const unsigned short* __restrict__ Wtb,
    const float* __restrict__ b1, const float* __restrict__ b2,
    const float* __restrict__ hg, const float* __restrict__ hb,
    const float* __restrict__ hw, const float* __restrict__ hbias,
    float* __restrict__ y)
{
    __shared__ float sR[16][264];
    __shared__ unsigned short sA[16][264];
    const int tid = threadIdx.x;
    const int lane = tid & 63, wave = tid >> 6;
    const int l15 = lane & 15, hi = lane >> 4;
    const int cbase = wave * 64;
    const int row0 = blockIdx.x * 16;
    {
        const int r = tid >> 4, cb = (tid & 15) * 4;
        #pragma unroll
        for (int q = 0; q < 4; ++q){
            *(float4*)&sR[r][cb + q*64] =
                *(const float4*)(hid + (size_t)(row0+r)*256 + cb + q*64);
            float4 mv = *(const float4*)(msgb + (size_t)(row0+r)*256 + cb + q*64);
            ushort4 u;
            u.x = f2bf(mv.x); u.y = f2bf(mv.y); u.z = f2bf(mv.z); u.w = f2bf(mv.w);
            *(ushort4*)&sA[r][cb + q*64] = u;
        }
    }
    __syncthreads();
    {
        f32x4 acc[4];
        #pragma unroll
        for (int t = 0; t < 4; ++t){ acc[t][0]=0.f; acc[t][1]=0.f; acc[t][2]=0.f; acc[t][3]=0.f; }
        mfma_gemm16(sA, Wtb + (size_t)4*65536, l15, hi, cbase, acc);
        #pragma unroll
        for (int t = 0; t < 4; ++t){
            int ct = cbase + t*16 + l15;
            float bbx = b1[ct];
            #pragma unroll
            for (int j = 0; j < 4; ++j)
                sA[hi*4 + j][ct] = f2bf(gelu_t(acc[t][j] + bbx));
        }
    }
    __syncthreads();
    {
        f32x4 acc[4];
        #pragma unroll
        for (int t = 0; t < 4; ++t){ acc[t][0]=0.f; acc[t][1]=0.f; acc[t][2]=0.f; acc[t][3]=0.f; }
        mfma_gemm16(sA, Wtb + (size_t)5*65536, l15, hi, cbase, acc);
        #pragma unroll
        for (int t = 0; t < 4; ++t){
            int ct = cbase + t*16 + l15;
            float bbx = b2[ct];
            #pragma unroll
            for (int j = 0; j < 4; ++j)
                sR[hi*4 + j][ct] += acc[t][j] + bbx;
        }
    }
    __syncthreads();
    {
        float4 gg = *(const float4*)(hg + lane*4);
        float4 bb = *(const float4*)(hb + lane*4);
        float4 wv = *(const float4*)(hw + lane*4);
        #pragma unroll
        for (int j = 0; j < 4; ++j){
            const int r = wave*4 + j;
            float4 v = *(const float4*)&sR[r][lane*4];
            float s = v.x+v.y+v.z+v.w;
            float q = v.x*v.x+v.y*v.y+v.z*v.z+v.w*v.w;
            #pragma unroll
            for (int m = 1; m < 64; m <<= 1){
                s += __shfl_xor(s, m, 64); q += __shfl_xor(q, m, 64);
            }
            float mu = s*(1.f/256.f);
            float rs = rsqrtf(q*(1.f/256.f) - mu*mu + 1e-5f);
            float p = gelu_t((v.x-mu)*rs*gg.x+bb.x)*wv.x
                    + gelu_t((v.y-mu)*rs*gg.y+bb.y)*wv.y
                    + gelu_t((v.z-mu)*rs*gg.z+bb.z)*wv.z
                    + gelu_t((v.w-mu)*rs*gg.w+bb.w)*wv.w;
            #pragma unroll
            for (int m = 1; m < 64; m <<= 1) p += __shfl_xor(p, m, 64);
            if (lane == 0) y[row0 + r] = p + hbias[0];
        }
    }
}

// ---------------- launch ----------------

extern "C" void kernel_launch(void* const* d_in, const int* in_sizes, int n_in,
                              void* d_out, int out_size, void* d_ws, size_t ws_size,
                              hipStream_t stream)
{
    (void)in_sizes; (void)n_in; (void)out_size; (void)ws_size;
    const float* X         = (const float*)d_in[0];
    const float* history   = (const float*)d_in[2];
    const float* enc_ln_g  = (const float*)d_in[3];
    const float* enc_ln_b  = (const float*)d_in[4];
    const float* enc_w1    = (const float*)d_in[5];
    const float* enc_b1    = (const float*)d_in[6];
    const float* enc_w2    = (const float*)d_in[7];
    const float* enc_b2    = (const float*)d_in[8];
    const float* proj_w    = (const float*)d_in[9];
    const float* proj_b    = (const float*)d_in[10];
    const float* fdg_B     = (const float*)d_in[11];
    const float* mixlog    = (const float*)d_in[12];
    const float* gblk_ln_g = (const float*)d_in[13];
    const float* gblk_ln_b = (const float*)d_in[14];
    const float* gblk_w1   = (const float*)d_in[15];
    const float* gblk_b1   = (const float*)d_in[16];
    const float* gblk_w2   = (const float*)d_in[17];
    const float* gblk_b2   = (const float*)d_in[18];
    const float* head_ln_g = (const float*)d_in[19];
    const float* head_ln_b = (const float*)d_in[20];
    const float* head_w    = (const float*)d_in[21];
    const float* head_b    = (const float*)d_in[22];

    float* ws  = (float*)d_ws;
    float* hid = ws;                              // NROWS*DH
    float* hh  = hid + (size_t)NROWS*DH;          // NROWS*DH
    float* msg = hh  + (size_t)NROWS*DH;          // NROWS*DH
    float* Znb = msg + (size_t)NROWS*DH;          // NROWS*16
    float* HnT = Znb + (size_t)NROWS*16;          // NB*64*N
    unsigned short* Wtb = (unsigned short*)(HnT + (size_t)NB*64*N);  // 6*65536 us
    float* boostA = (float*)(Wtb + (size_t)6*65536);   // NROWS*24
    int*   bidxA  = (int*)(boostA + (size_t)NROWS*24); // NROWS*24
    int*   cntA   = bidxA + (size_t)NROWS*24;          // NROWS
    int*   flagA  = cntA + NROWS;                      // NROWS
    float* y   = (float*)d_out;

    k_wcvt<<<dim3(8,8,6), 256, 0, stream>>>(
        (const float*)d_in[25], (const float*)d_in[27],
        (const float*)d_in[31], (const float*)d_in[33],
        gblk_w1, gblk_w2, Wtb);
    k_enc<<<NROWS/8, 256, 0, stream>>>(X, enc_ln_g, enc_ln_b, enc_w1, enc_b1, enc_w2, enc_b2,
                                       proj_w, proj_b, fdg_B, hid, Znb);
    k_hist<<<NROWS/4, 256, 0, stream>>>(history, HnT);
    k_corrtop<<<dim3(125, NB), 256, 0, stream>>>(HnT, mixlog, bidxA, boostA, cntA, flagA);
    k_fix<<<NROWS, 64, 0, stream>>>(HnT, mixlog, bidxA, boostA, cntA, flagA);
    k_mlp2<<<NROWS/16, 256, 0, stream>>>(hid, Wtb,
        (const float*)d_in[23], (const float*)d_in[24],
        (const float*)d_in[26], (const float*)d_in[28],
        (const float*)d_in[29], (const float*)d_in[30],
        (const float*)d_in[32], (const float*)d_in[34],
        gblk_ln_g, gblk_ln_b, hh);
    k_sel2<<<NROWS/4, 256, 0, stream>>>(Znb, hh, mixlog, bidxA, boostA, cntA, msg);
    k_gblk<<<NROWS/16, 256, 0, stream>>>(hid, msg, Wtb, gblk_b1, gblk_b2,
                                         head_ln_g, head_ln_b, head_w, head_b, y);
}